// Round 1
// baseline (318.221 us; speedup 1.0000x reference)
//
#include <hip/hip_runtime.h>

// Problem constants (fixed by reference setup)
#define B_ 4
#define N_ 96
#define T_ 512
#define K_ 12
#define G_ 8
#define NIMG (B_*K_*T_)   // 24576 images

typedef _Float16 half8 __attribute__((ext_vector_type(8)));
typedef float floatx4 __attribute__((ext_vector_type(4)));

// ---------- math helpers ----------
__device__ __forceinline__ float softplusf(float x) {
    return (x > 15.0f) ? x : log1pf(__expf(x));
}
__device__ __forceinline__ float fast_tanhf(float x) {
    float ax = fabsf(x);
    float e  = __expf(-2.0f * ax);
    float r  = (1.0f - e) * __builtin_amdgcn_rcpf(1.0f + e);
    return copysignf(r, x);
}
// exact-ish GELU: Abramowitz-Stegun 7.1.26 erf (abs err 1.5e-7)
__device__ __forceinline__ float geluf(float x) {
    float z  = 0.70710678118654752f * x;
    float az = fabsf(z);
    float t  = __builtin_amdgcn_rcpf(fmaf(0.3275911f, az, 1.0f));
    float poly = t * fmaf(t, fmaf(t, fmaf(t, fmaf(t, 1.061405429f, -1.453152027f),
                       1.421413741f), -0.284496736f), 0.254829592f);
    float e  = __expf(-az * az);
    float er = fmaf(-poly, e, 1.0f);     // erf(|z|)
    er = copysignf(er, z);
    return 0.5f * x * (1.0f + er);
}

// ---------- K0: lead constants + weight repack ----------
// ws layout:
//   leads  (float)   @ 0      : 12 * 18  (L[3], e1[3], e2[3], Y[9])
//   W1p    (_Float16)@ 1024   : [32 co][40 k]      (k = tap*2+ci, zero-padded 18..39)
//   W2p    (_Float16)@ 4096   : [9 tap][32 co][40 ci] (ci zero-padded 32..39)
//   splat  (_Float16)@ 32768  : [24576 img][2 ch][64 pix]
__global__ void setup_kernel(const float* __restrict__ ra, const float* __restrict__ la,
                             const float* __restrict__ ll, const float* __restrict__ chest,
                             const float* __restrict__ w1, const float* __restrict__ w2,
                             float* __restrict__ leads, _Float16* __restrict__ W1p,
                             _Float16* __restrict__ W2p) {
    int tid = threadIdx.x;
    if (tid < 12) {
        int k = tid;
        float vx, vy, vz;
        if      (k == 0) { vx = la[0]-ra[0]; vy = la[1]-ra[1]; vz = la[2]-ra[2]; }
        else if (k == 1) { vx = ll[0]-ra[0]; vy = ll[1]-ra[1]; vz = ll[2]-ra[2]; }
        else if (k == 2) { vx = ll[0]-la[0]; vy = ll[1]-la[1]; vz = ll[2]-la[2]; }
        else if (k == 3) { vx = ra[0]-0.5f*(la[0]+ll[0]); vy = ra[1]-0.5f*(la[1]+ll[1]); vz = ra[2]-0.5f*(la[2]+ll[2]); }
        else if (k == 4) { vx = la[0]-0.5f*(ra[0]+ll[0]); vy = la[1]-0.5f*(ra[1]+ll[1]); vz = la[2]-0.5f*(ra[2]+ll[2]); }
        else if (k == 5) { vx = ll[0]-0.5f*(ra[0]+la[0]); vy = ll[1]-0.5f*(ra[1]+la[1]); vz = ll[2]-0.5f*(ra[2]+la[2]); }
        else             { vx = chest[(k-6)*3+0]; vy = chest[(k-6)*3+1]; vz = chest[(k-6)*3+2]; }
        float n = fmaxf(sqrtf(vx*vx+vy*vy+vz*vz), 1e-6f);
        float Lx = vx/n, Ly = vy/n, Lz = vz/n;
        // e1 = cross(L, x-axis) = (0, Lz, -Ly); if tiny, cross(L, y-axis) = (-Lz, 0, Lx)
        float ex = 0.0f, ey = Lz, ez = -Ly;
        if (sqrtf(ey*ey + ez*ez) < 1e-4f) { ex = -Lz; ey = 0.0f; ez = Lx; }
        float en = fmaxf(sqrtf(ex*ex+ey*ey+ez*ez), 1e-6f);
        ex /= en; ey /= en; ez /= en;
        // e2 = normalize(cross(e1, L))
        float fx = ey*Lz - ez*Ly, fy = ez*Lx - ex*Lz, fz = ex*Ly - ey*Lx;
        float fn = fmaxf(sqrtf(fx*fx+fy*fy+fz*fz), 1e-6f);
        fx /= fn; fy /= fn; fz /= fn;
        float* o = leads + k*18;
        o[0]=Lx; o[1]=Ly; o[2]=Lz;
        o[3]=ex; o[4]=ey; o[5]=ez;
        o[6]=fx; o[7]=fy; o[8]=fz;
        o[9]  = 0.282095f;
        o[10] = -0.488603f*Ly;
        o[11] =  0.488603f*Lz;
        o[12] = -0.488603f*Lx;
        o[13] =  1.092548f*Lx*Ly;
        o[14] = -1.092548f*Ly*Lz;
        o[15] =  0.315392f*fmaf(3.0f*Lz, Lz, -1.0f);
        o[16] = -1.092548f*Lx*Lz;
        o[17] =  0.546274f*(Lx*Lx - Ly*Ly);
    }
    // conv1 weights: W1p[co][k], k = tap*2 + ci, k in [0,18) valid
    for (int e = tid; e < 32*40; e += blockDim.x) {
        int co = e/40, kk = e%40;
        float val = 0.0f;
        if (kk < 18) { int ci = kk & 1, tap = kk >> 1; val = w1[(co*2+ci)*9 + tap]; }
        W1p[e] = (_Float16)val;
    }
    // conv2 weights: W2p[tap][co][ci]
    for (int e = tid; e < 9*32*40; e += blockDim.x) {
        int tap = e/1280, rem = e%1280, co = rem/40, ci = rem%40;
        float val = (ci < 32) ? w2[(co*32+ci)*9 + tap] : 0.0f;
        W2p[e] = (_Float16)val;
    }
}

// ---------- K1: splat ----------
// grid 384 blocks, block (64,4): x = t within 64-tile, y = n-chunk (24 n each).
// 128 fp32 register accumulators per thread; LDS atomic reduce across the 4 n-chunks.
__global__ __launch_bounds__(256, 2) void splat_kernel(
    const float* __restrict__ mu,  const float* __restrict__ sg0,
    const float* __restrict__ sgv, const float* __restrict__ amp,
    const float* __restrict__ shb, const float* __restrict__ shv,
    const float* __restrict__ p0,  const float* __restrict__ pv,
    const float* __restrict__ tau_raw, const float* __restrict__ da_raw,
    const float* __restrict__ leads, _Float16* __restrict__ outp) {
    int tt   = threadIdx.x;           // 0..63
    int ncv  = threadIdx.y;           // 0..3
    int flat = ncv*64 + tt;
    int Lb = blockIdx.x;
    int t0 = (Lb & 7) << 6;
    int k  = (Lb >> 3) % 12;
    int b  = Lb / 96;

    const float* ld = leads + k*18;
    float Lx=ld[0], Ly=ld[1], Lz=ld[2];
    float e1x=ld[3], e1y=ld[4], e1z=ld[5];
    float e2x=ld[6], e2y=ld[7], e2z=ld[8];
    float Y[9];
#pragma unroll
    for (int m=0;m<9;m++) Y[m]=ld[9+m];

    float tau = softplusf(tau_raw[0]) + 0.06f;
    float cc2 = 0.5f/(tau*tau);
    float gamma = softplusf(da_raw[0]) + 1e-6f;
    const float S = 2.0f/7.0f;   // grid step of linspace(-1,1,8)
    // ku[w] = exp(-c(u-g_w)^2) = exp(-c*du^2) * exp(2cS*du)^w * q[w],  du=u+1, q[w]=exp(-c(wS)^2)
    float q[8];
#pragma unroll
    for (int w=0; w<8; ++w) { float gw = S*(float)w; q[w] = __expf(-cc2*gw*gw); }

    float tf = (float)(t0 + tt) * (1.0f/511.0f);
    float accP[64], accS[64];
#pragma unroll
    for (int i=0;i<64;i++){ accP[i]=0.f; accS[i]=0.f; }

    int n0 = ncv*24;
    for (int n = n0; n < n0+24; ++n) {
        int base = b*N_ + n;
        float dt  = tf - mu[base];
        float sig = softplusf(fmaf(sgv[base], dt, sg0[base])) + 1e-3f;
        float z   = dt * __builtin_amdgcn_rcpf(sig);
        float gauss = amp[base] * __expf(-0.5f*z*z);
        float prx = fmaf(pv[base*3+0], dt, p0[base*3+0]);
        float pry = fmaf(pv[base*3+1], dt, p0[base*3+1]);
        float prz = fmaf(pv[base*3+2], dt, p0[base*3+2]);
        float nr  = sqrtf(prx*prx + pry*pry + prz*prz);
        float ncl = fmaxf(nr, 1e-8f);
        float th  = fast_tanhf(ncl);
        float scl = th * __builtin_amdgcn_rcpf(ncl);
        float px = prx*scl, py = pry*scl, pz = prz*scl;
        float uu = fast_tanhf(px*e1x + py*e1y + pz*e1z);
        float vv = fast_tanhf(px*e2x + py*e2y + pz*e2z);
        float pn = fmaxf(th, 1e-8f);            // == max(|p_pos|, 1e-8)
        float cosl = (px*Lx + py*Ly + pz*Lz) * __builtin_amdgcn_rcpf(pn);
        float hem  = fmaxf(cosl, 0.0f);
        float ccl  = fminf(fmaxf(cosl, -0.999999f), 0.999999f);
        float theta = acosf(ccl);
        float wgt = hem * __expf(-gamma*theta*theta);
        float A = gauss * wgt;
        if (A != 0.0f) {
            float shp = 0.0f;
#pragma unroll
            for (int m=0;m<9;m++) shp += fmaf(shv[base*9+m], dt, shb[base*9+m]) * Y[m];
            float As = A * shp;
            float du = uu + 1.0f, dv = vv + 1.0f;
            float bu = __expf(-cc2*du*du);
            float bv = __expf(-cc2*dv*dv);
            float ru = __expf((2.0f*cc2*S)*du);
            float rv = __expf((2.0f*cc2*S)*dv);
            float ku[8], kv[8];
            float rw = bu;
#pragma unroll
            for (int w=0;w<8;++w){ ku[w] = rw*q[w]; rw *= ru; }
            rw = bv;
#pragma unroll
            for (int h=0;h<8;++h){ kv[h] = rw*q[h]; rw *= rv; }
#pragma unroll
            for (int h=0;h<8;++h) {
                float tp = A*kv[h], ts = As*kv[h];
#pragma unroll
                for (int w=0;w<8;++w) {
                    accP[h*8+w] = fmaf(tp, ku[w], accP[h*8+w]);
                    accS[h*8+w] = fmaf(ts, ku[w], accS[h*8+w]);
                }
            }
        }
    }
    // reduce the 4 n-chunks via LDS atomics (row stride 130 breaks bank aliasing)
    __shared__ float red[64*130];
    for (int i = flat; i < 64*130; i += 256) red[i] = 0.0f;
    __syncthreads();
#pragma unroll
    for (int i=0;i<64;i++) {
        atomicAdd(&red[tt*130 + i],      accP[i]);
        atomicAdd(&red[tt*130 + 64 + i], accS[i]);
    }
    __syncthreads();
    int imgbase = (b*12 + k)*T_ + t0;
    for (int ii = 0; ii < 32; ++ii) {
        int e = ii*256 + flat;
        int r = e >> 7, c = e & 127;
        outp[(imgbase + r)*128 + c] = (_Float16)red[r*130 + c];
    }
}

// ---------- K2: CNN readout ----------
// 1 wave per image, 4 images per 256-thread block, grid = 6144.
// conv1: implicit GEMM M=64,N=32,K=18(pad 32); conv2: M=64,N=32,K=288 (9 taps x 32ch).
__global__ __launch_bounds__(256, 2) void cnn_kernel(
    const _Float16* __restrict__ splat, const _Float16* __restrict__ W1p,
    const _Float16* __restrict__ W2p,  const float* __restrict__ b1,
    const float* __restrict__ b2,      const float* __restrict__ fcw,
    const float* __restrict__ fcb,     float* __restrict__ outv) {
    __shared__ __align__(16) _Float16 sW2[9*32*40];   // [tap][co][ci pad 40]
    __shared__ __align__(16) _Float16 sH1[4][100*40]; // per img: [10x10 padded pix][ch pad 40]
    __shared__ __align__(16) _Float16 sW1[32*40];     // [co][k pad 40]
    __shared__ __align__(16) _Float16 sIn[4][200];    // per img: [2 ch][10x10 padded]
    int tid = threadIdx.x;
    {   // stage weights (already padded in ws)
        const unsigned int* s2 = (const unsigned int*)W2p; unsigned int* d2 = (unsigned int*)sW2;
        for (int i = tid; i < 9*32*40/2; i += 256) d2[i] = s2[i];
        const unsigned int* s1 = (const unsigned int*)W1p; unsigned int* d1 = (unsigned int*)sW1;
        for (int i = tid; i < 32*40/2; i += 256) d1[i] = s1[i];
    }
    int wv = tid >> 6, lane = tid & 63;
    int img = blockIdx.x*4 + wv;
    _Float16* H  = sH1[wv];
    _Float16* IN = sIn[wv];
    {   // zero halo regions
        unsigned long long* hz = (unsigned long long*)H;
        for (int i = lane; i < 1000; i += 64) hz[i] = 0ull;
        unsigned int* iz = (unsigned int*)IN;
        for (int i = lane; i < 100; i += 64) iz[i] = 0u;
    }
    __syncthreads();
    // stage input 2x8x8 into padded 2x10x10
#pragma unroll
    for (int ii = 0; ii < 2; ++ii) {
        int i = ii*64 + lane;
        int ci = i >> 6, p = i & 63;
        IN[ci*100 + ((p>>3)+1)*10 + (p&7) + 1] = splat[img*128 + i];
    }
    __syncthreads();

    int r = lane & 15, qd = lane >> 4;
    // ---- conv1 ----
    floatx4 c1[2][4];
#pragma unroll
    for (int nt=0;nt<2;nt++)
#pragma unroll
      for (int mt=0;mt<4;mt++) c1[nt][mt] = (floatx4){0.f,0.f,0.f,0.f};
    half8 bw[2];
#pragma unroll
    for (int nt=0;nt<2;nt++) bw[nt] = *(const half8*)&sW1[(nt*16+r)*40 + qd*8];
#pragma unroll
    for (int mt=0;mt<4;mt++) {
        int p = mt*16 + r, py = p>>3, px = p&7;
        half8 a;
#pragma unroll
        for (int j=0;j<8;j++) {
            int kk = qd*8 + j;
            int ci = kk & 1;
            int tap = kk >> 1; if (tap > 8) tap = 8;   // clamp keeps address in-bounds
            int ky = tap/3, kx = tap - ky*3;
            _Float16 val = IN[ci*100 + (py+ky)*10 + (px+kx)];
            if (kk >= 18) val = (_Float16)0.0f;
            a[j] = val;
        }
#pragma unroll
        for (int nt=0;nt<2;nt++)
            c1[nt][mt] = __builtin_amdgcn_mfma_f32_16x16x32_f16(a, bw[nt], c1[nt][mt], 0, 0, 0);
    }
    // bias + gelu -> H (padded [pix][ch])
    float bias1[2] = { b1[r], b1[16+r] };
#pragma unroll
    for (int nt=0;nt<2;nt++)
#pragma unroll
      for (int mt=0;mt<4;mt++)
#pragma unroll
        for (int j=0;j<4;j++) {
            int p = mt*16 + qd*4 + j, py = p>>3, px = p&7;
            float g = geluf(c1[nt][mt][j] + bias1[nt]);
            H[((py+1)*10 + (px+1))*40 + nt*16 + r] = (_Float16)g;
        }
    __syncthreads();
    // ---- conv2 ----
    floatx4 c2[2][4];
#pragma unroll
    for (int nt=0;nt<2;nt++)
#pragma unroll
      for (int mt=0;mt<4;mt++) c2[nt][mt] = (floatx4){0.f,0.f,0.f,0.f};
#pragma unroll
    for (int tap=0; tap<9; ++tap) {
        int ky = tap/3, kx = tap - (tap/3)*3;
        half8 wb[2];
#pragma unroll
        for (int nt=0;nt<2;nt++) wb[nt] = *(const half8*)&sW2[tap*1280 + (nt*16+r)*40 + qd*8];
#pragma unroll
        for (int mt=0;mt<4;mt++) {
            int p = mt*16 + r, py = p>>3, px = p&7;
            half8 a = *(const half8*)&H[((py+ky)*10 + (px+kx))*40 + qd*8];
#pragma unroll
            for (int nt=0;nt<2;nt++)
                c2[nt][mt] = __builtin_amdgcn_mfma_f32_16x16x32_f16(a, wb[nt], c2[nt][mt], 0, 0, 0);
        }
    }
    // bias + gelu + mean-pool + fc
    float bias2[2] = { b2[r], b2[16+r] };
    float chs0 = 0.f, chs1 = 0.f;
#pragma unroll
    for (int mt=0;mt<4;mt++)
#pragma unroll
      for (int j=0;j<4;j++) {
        chs0 += geluf(c2[0][mt][j] + bias2[0]);
        chs1 += geluf(c2[1][mt][j] + bias2[1]);
      }
    chs0 += __shfl_xor(chs0, 16); chs0 += __shfl_xor(chs0, 32);
    chs1 += __shfl_xor(chs1, 16); chs1 += __shfl_xor(chs1, 32);
    float tot = (chs0 * fcw[r] + chs1 * fcw[16+r]) * (1.0f/64.0f);
    tot += __shfl_xor(tot, 1); tot += __shfl_xor(tot, 2);
    tot += __shfl_xor(tot, 4); tot += __shfl_xor(tot, 8);
    tot += fcb[0];
    if (lane == 0) {
        int t = img & 511, bk = img >> 9;
        int kk = bk % 12, bb = bk / 12;
        // faithful torch permutation: out[b, :, :].flat = scalars[b].T.flat
        outv[(bb*T_ + t)*12 + kk] = tot;
    }
}

extern "C" void kernel_launch(void* const* d_in, const int* in_sizes, int n_in,
                              void* d_out, int out_size, void* d_ws, size_t ws_size,
                              hipStream_t stream) {
    const float* mu   = (const float*)d_in[0];
    const float* sg0  = (const float*)d_in[1];
    const float* sgv  = (const float*)d_in[2];
    const float* amp  = (const float*)d_in[3];
    const float* shb  = (const float*)d_in[4];
    const float* shv  = (const float*)d_in[5];
    const float* p0   = (const float*)d_in[6];
    const float* pvel = (const float*)d_in[7];
    const float* taur = (const float*)d_in[8];
    const float* dar  = (const float*)d_in[9];
    const float* ra   = (const float*)d_in[10];
    const float* la   = (const float*)d_in[11];
    const float* ll   = (const float*)d_in[12];
    const float* chest= (const float*)d_in[13];
    const float* w1   = (const float*)d_in[14];
    const float* b1   = (const float*)d_in[15];
    const float* w2   = (const float*)d_in[16];
    const float* b2   = (const float*)d_in[17];
    const float* fcw  = (const float*)d_in[18];
    const float* fcb  = (const float*)d_in[19];

    char* ws = (char*)d_ws;
    float*     leads = (float*)ws;
    _Float16*  W1p   = (_Float16*)(ws + 1024);
    _Float16*  W2p   = (_Float16*)(ws + 4096);
    _Float16*  splat = (_Float16*)(ws + 32768);

    setup_kernel<<<1, 256, 0, stream>>>(ra, la, ll, chest, w1, w2, leads, W1p, W2p);
    splat_kernel<<<384, dim3(64,4), 0, stream>>>(mu, sg0, sgv, amp, shb, shv, p0, pvel,
                                                 taur, dar, leads, splat);
    cnn_kernel<<<NIMG/4, 256, 0, stream>>>(splat, W1p, W2p, b1, b2, fcw, fcb, (float*)d_out);
}

// Round 2
// 248.004 us; speedup vs baseline: 1.2831x; 1.2831x over previous
//
#include <hip/hip_runtime.h>

// Problem constants (fixed by reference setup)
#define B_ 4
#define N_ 96
#define T_ 512
#define G_ 8
#define NIMG (B_*12*T_)   // 24576 images

typedef _Float16 half8 __attribute__((ext_vector_type(8)));
typedef float floatx4 __attribute__((ext_vector_type(4)));

// ---------- math helpers ----------
__device__ __forceinline__ float softplusf(float x) {
    return (x > 15.0f) ? x : __logf(1.0f + __expf(x));
}
__device__ __forceinline__ float fast_tanhf(float x) {
    float ax = fabsf(x);
    float e  = __expf(-2.0f * ax);
    float r  = (1.0f - e) * __builtin_amdgcn_rcpf(1.0f + e);
    return copysignf(r, x);
}
// GELU with 3-term Abramowitz-Stegun erf (abs err 2.5e-5)
__device__ __forceinline__ float geluf(float x) {
    float z  = 0.70710678118654752f * x;
    float az = fabsf(z);
    float t  = __builtin_amdgcn_rcpf(fmaf(0.47047f, az, 1.0f));
    float poly = t * fmaf(t, fmaf(t, 0.7478556f, -0.0958798f), 0.3480242f);
    float e  = __expf(-az * az);
    float er = fmaf(-poly, e, 1.0f);     // erf(|z|)
    er = copysignf(er, z);
    return 0.5f * x * (1.0f + er);
}

// ---------- K1: splat ----------
// grid 768 blocks = (b, k, 16 t-tiles of 32). block (64,4):
//   lane = tt(0..31) + 32*ch ; threadIdx.y = n-chunk (24 n each).
// 64 fp32 accumulators/thread (one channel); LDS atomic reduce over 4 n-chunks.
// Blocks 0..10 additionally repack conv weights into ws (consumed by cnn_kernel,
// ordering guaranteed by the kernel boundary).
__global__ __launch_bounds__(256, 3) void splat_kernel(
    const float* __restrict__ mu,  const float* __restrict__ sg0,
    const float* __restrict__ sgv, const float* __restrict__ amp,
    const float* __restrict__ shb, const float* __restrict__ shv,
    const float* __restrict__ p0,  const float* __restrict__ pv,
    const float* __restrict__ tau_raw, const float* __restrict__ da_raw,
    const float* __restrict__ ra, const float* __restrict__ la,
    const float* __restrict__ ll, const float* __restrict__ chest,
    const float* __restrict__ w1, const float* __restrict__ w2,
    _Float16* __restrict__ outp, _Float16* __restrict__ W1p,
    _Float16* __restrict__ W2p) {
    int lx   = threadIdx.x;           // 0..63
    int nc   = threadIdx.y;           // 0..3
    int flat = nc*64 + lx;
    int tt = lx & 31, ch = lx >> 5;
    int Lb = blockIdx.x;
    int t0 = (Lb & 15) << 5;
    int k  = (Lb >> 4) % 12;
    int b  = Lb / 192;

    // ---- weight repack (blocks 0..10 only; trivial extra work) ----
    if (Lb < 10) {
        for (int e = Lb*1152 + flat; e < Lb*1152 + 1152; e += 256) {
            int tap = e/1280, rem = e - tap*1280, co = rem/40, ci = rem - co*40;
            float val = (ci < 32) ? w2[(co*32+ci)*9 + tap] : 0.0f;
            W2p[e] = (_Float16)val;          // [tap][co][ci pad 40]
        }
    } else if (Lb == 10) {
        for (int e = flat; e < 32*40; e += 256) {
            int co = e/40, kk = e - co*40;
            float val = 0.0f;
            if (kk < 18) { int ci = kk & 1, tap = kk >> 1; val = w1[(co*2+ci)*9 + tap]; }
            W1p[e] = (_Float16)val;          // [co][k pad 40]
        }
    }

    // ---- lead constants (wave-uniform, ~50 ops once per block) ----
    float vx, vy, vz;
    if      (k == 0) { vx = la[0]-ra[0]; vy = la[1]-ra[1]; vz = la[2]-ra[2]; }
    else if (k == 1) { vx = ll[0]-ra[0]; vy = ll[1]-ra[1]; vz = ll[2]-ra[2]; }
    else if (k == 2) { vx = ll[0]-la[0]; vy = ll[1]-la[1]; vz = ll[2]-la[2]; }
    else if (k == 3) { vx = ra[0]-0.5f*(la[0]+ll[0]); vy = ra[1]-0.5f*(la[1]+ll[1]); vz = ra[2]-0.5f*(la[2]+ll[2]); }
    else if (k == 4) { vx = la[0]-0.5f*(ra[0]+ll[0]); vy = la[1]-0.5f*(ra[1]+ll[1]); vz = la[2]-0.5f*(ra[2]+ll[2]); }
    else if (k == 5) { vx = ll[0]-0.5f*(ra[0]+la[0]); vy = ll[1]-0.5f*(ra[1]+la[1]); vz = ll[2]-0.5f*(ra[2]+la[2]); }
    else             { vx = chest[(k-6)*3+0]; vy = chest[(k-6)*3+1]; vz = chest[(k-6)*3+2]; }
    float nn = fmaxf(sqrtf(vx*vx+vy*vy+vz*vz), 1e-6f);
    float Lx = vx/nn, Ly = vy/nn, Lz = vz/nn;
    // e1 = cross(L, x-axis) = (0, Lz, -Ly); if tiny, cross(L, y-axis) = (-Lz, 0, Lx)
    float e1x = 0.0f, e1y = Lz, e1z = -Ly;
    if (sqrtf(e1y*e1y + e1z*e1z) < 1e-4f) { e1x = -Lz; e1y = 0.0f; e1z = Lx; }
    float en = fmaxf(sqrtf(e1x*e1x+e1y*e1y+e1z*e1z), 1e-6f);
    e1x /= en; e1y /= en; e1z /= en;
    float e2x = e1y*Lz - e1z*Ly, e2y = e1z*Lx - e1x*Lz, e2z = e1x*Ly - e1y*Lx;
    float fn = fmaxf(sqrtf(e2x*e2x+e2y*e2y+e2z*e2z), 1e-6f);
    e2x /= fn; e2y /= fn; e2z /= fn;
    float Y[9];
    Y[0] =  0.282095f;
    Y[1] = -0.488603f*Ly;
    Y[2] =  0.488603f*Lz;
    Y[3] = -0.488603f*Lx;
    Y[4] =  1.092548f*Lx*Ly;
    Y[5] = -1.092548f*Ly*Lz;
    Y[6] =  0.315392f*fmaf(3.0f*Lz, Lz, -1.0f);
    Y[7] = -1.092548f*Lx*Lz;
    Y[8] =  0.546274f*(Lx*Lx - Ly*Ly);

    float tau = softplusf(tau_raw[0]) + 0.06f;
    float cc2 = 0.5f/(tau*tau);
    float gamma = softplusf(da_raw[0]) + 1e-6f;
    const float S = 2.0f/7.0f;   // grid step of linspace(-1,1,8)
    // ku[w] = exp(-c(u-g_w)^2) = exp(-c*du^2) * exp(2cS*du)^w * q[w],  du=u+1
    float q[8];
#pragma unroll
    for (int w = 0; w < 8; ++w) { float gw = S*(float)w; q[w] = __expf(-cc2*gw*gw); }

    float tf = (float)(t0 + tt) * (1.0f/511.0f);
    float acc[64];
#pragma unroll
    for (int i = 0; i < 64; ++i) acc[i] = 0.0f;

    int n0 = nc*24;
    for (int n = n0; n < n0+24; ++n) {
        int base = b*N_ + n;
        float dt  = tf - mu[base];
        float sig = softplusf(fmaf(sgv[base], dt, sg0[base])) + 1e-3f;
        float z   = dt * __builtin_amdgcn_rcpf(sig);
        float gauss = amp[base] * __expf(-0.5f*z*z);
        float prx = fmaf(pv[base*3+0], dt, p0[base*3+0]);
        float pry = fmaf(pv[base*3+1], dt, p0[base*3+1]);
        float prz = fmaf(pv[base*3+2], dt, p0[base*3+2]);
        float nr  = sqrtf(prx*prx + pry*pry + prz*prz);
        float ncl = fmaxf(nr, 1e-8f);
        float th  = fast_tanhf(ncl);
        float scl = th * __builtin_amdgcn_rcpf(ncl);
        float px = prx*scl, py = pry*scl, pz = prz*scl;
        float pn = fmaxf(th, 1e-8f);            // == max(|p_pos|, 1e-8)
        float cosl = (px*Lx + py*Ly + pz*Lz) * __builtin_amdgcn_rcpf(pn);
        float hem  = fmaxf(cosl, 0.0f);
        if (gauss != 0.0f && hem > 0.0f) {
            // acos on [0,1): A-S 4.4.45 poly, abs err 6.7e-5
            float c = fminf(cosl, 0.999999f);
            float s = sqrtf(1.0f - c);
            float theta = s * fmaf(c, fmaf(c, fmaf(c, -0.0187293f, 0.0742610f),
                                   -0.2121144f), 1.5707288f);
            float A = gauss * hem * __expf(-gamma*theta*theta);
            float uu = fast_tanhf(px*e1x + py*e1y + pz*e1z);
            float vv = fast_tanhf(px*e2x + py*e2y + pz*e2z);
            float Ach = A;
            if (ch) {                            // sh channel: lanes 32..63
                float shp = 0.0f;
#pragma unroll
                for (int m = 0; m < 9; ++m)
                    shp += fmaf(shv[base*9+m], dt, shb[base*9+m]) * Y[m];
                Ach = A * shp;
            }
            float du = uu + 1.0f, dv = vv + 1.0f;
            float bu = __expf(-cc2*du*du);
            float bv = __expf(-cc2*dv*dv);
            float ru = __expf((2.0f*cc2*S)*du);
            float rv = __expf((2.0f*cc2*S)*dv);
            float ku[8];
            float rw = bu;
#pragma unroll
            for (int w = 0; w < 8; ++w) { ku[w] = rw*q[w]; rw *= ru; }
            rw = bv;
#pragma unroll
            for (int h = 0; h < 8; ++h) {
                float tp = (rw*q[h])*Ach; rw *= rv;
#pragma unroll
                for (int w = 0; w < 8; ++w)
                    acc[h*8+w] = fmaf(tp, ku[w], acc[h*8+w]);
            }
        }
    }
    // reduce the 4 n-chunks via LDS atomics (row stride 130 -> 2-way bank alias, free)
    __shared__ float red[32*130];
    for (int i = flat; i < 32*130; i += 256) red[i] = 0.0f;
    __syncthreads();
#pragma unroll
    for (int i = 0; i < 64; ++i)
        atomicAdd(&red[tt*130 + ch*64 + i], acc[i]);
    __syncthreads();
    // write out 32 x 128 f16, 16 consecutive per thread (two 16B stores)
    int imgbase = (b*12 + k)*T_ + t0;
    int e0 = flat*16, r = e0 >> 7, c0 = e0 & 127;
    half8 h0, h1;
#pragma unroll
    for (int j = 0; j < 8; ++j) {
        h0[j] = (_Float16)red[r*130 + c0 + j];
        h1[j] = (_Float16)red[r*130 + c0 + 8 + j];
    }
    *(half8*)&outp[(imgbase + r)*128 + c0]     = h0;
    *(half8*)&outp[(imgbase + r)*128 + c0 + 8] = h1;
}

// ---------- K2: CNN readout ----------
// 1 wave per image, 4 images per 256-thread block, grid = 6144.
// Weights read straight from global (L1-resident after first block per CU);
// LDS holds only input patch + conv1 activations -> ~34 KB -> 4 blocks/CU.
__global__ __launch_bounds__(256, 4) void cnn_kernel(
    const _Float16* __restrict__ splat, const _Float16* __restrict__ W1p,
    const _Float16* __restrict__ W2p,  const float* __restrict__ b1,
    const float* __restrict__ b2,      const float* __restrict__ fcw,
    const float* __restrict__ fcb,     float* __restrict__ outv) {
    __shared__ __align__(16) _Float16 sH1[4][100*40]; // per img: [10x10 padded pix][ch pad 40]
    __shared__ __align__(16) _Float16 sIn[4][200];    // per img: [2 ch][10x10 padded]
    int tid = threadIdx.x;
    int wv = tid >> 6, lane = tid & 63;
    int img = blockIdx.x*4 + wv;
    _Float16* H  = sH1[wv];
    _Float16* IN = sIn[wv];
    {   // zero halo regions (wave-private; same-wave DS ops are pipe-ordered)
        unsigned long long* hz = (unsigned long long*)H;
        for (int i = lane; i < 1000; i += 64) hz[i] = 0ull;
        unsigned int* iz = (unsigned int*)IN;
        for (int i = lane; i < 100; i += 64) iz[i] = 0u;
    }
    // stage input 2x8x8 into padded 2x10x10
#pragma unroll
    for (int ii = 0; ii < 2; ++ii) {
        int i = ii*64 + lane;
        int ci = i >> 6, p = i & 63;
        IN[ci*100 + ((p>>3)+1)*10 + (p&7) + 1] = splat[img*128 + i];
    }
    __syncthreads();

    int r = lane & 15, qd = lane >> 4;
    // ---- conv1: M=64 pix, N=32 ch, K=18 (pad 32) ----
    floatx4 c1[2][4];
#pragma unroll
    for (int nt = 0; nt < 2; ++nt)
#pragma unroll
      for (int mt = 0; mt < 4; ++mt) c1[nt][mt] = (floatx4){0.f,0.f,0.f,0.f};
    half8 bw[2];
#pragma unroll
    for (int nt = 0; nt < 2; ++nt)
        bw[nt] = *(const half8*)&W1p[(nt*16+r)*40 + qd*8];
#pragma unroll
    for (int mt = 0; mt < 4; ++mt) {
        int p = mt*16 + r, py = p>>3, px = p&7;
        half8 a;
#pragma unroll
        for (int j = 0; j < 8; ++j) {
            int kk = qd*8 + j;
            int ci = kk & 1;
            int tap = kk >> 1; if (tap > 8) tap = 8;   // clamp keeps address in-bounds
            int ky = tap/3, kx = tap - ky*3;
            _Float16 val = IN[ci*100 + (py+ky)*10 + (px+kx)];
            if (kk >= 18) val = (_Float16)0.0f;
            a[j] = val;
        }
#pragma unroll
        for (int nt = 0; nt < 2; ++nt)
            c1[nt][mt] = __builtin_amdgcn_mfma_f32_16x16x32_f16(a, bw[nt], c1[nt][mt], 0, 0, 0);
    }
    // bias + gelu -> H (padded [pix][ch])
    float bias1[2] = { b1[r], b1[16+r] };
#pragma unroll
    for (int nt = 0; nt < 2; ++nt)
#pragma unroll
      for (int mt = 0; mt < 4; ++mt)
#pragma unroll
        for (int j = 0; j < 4; ++j) {
            int p = mt*16 + qd*4 + j, py = p>>3, px = p&7;
            float g = geluf(c1[nt][mt][j] + bias1[nt]);
            H[((py+1)*10 + (px+1))*40 + nt*16 + r] = (_Float16)g;
        }
    __syncthreads();
    // ---- conv2: M=64, N=32, K=288 (9 taps x 32 ch) ----
    floatx4 c2[2][4];
#pragma unroll
    for (int nt = 0; nt < 2; ++nt)
#pragma unroll
      for (int mt = 0; mt < 4; ++mt) c2[nt][mt] = (floatx4){0.f,0.f,0.f,0.f};
#pragma unroll
    for (int tap = 0; tap < 9; ++tap) {
        int ky = tap/3, kx = tap - (tap/3)*3;
        half8 wb[2];
#pragma unroll
        for (int nt = 0; nt < 2; ++nt)
            wb[nt] = *(const half8*)&W2p[tap*1280 + (nt*16+r)*40 + qd*8];
#pragma unroll
        for (int mt = 0; mt < 4; ++mt) {
            int p = mt*16 + r, py = p>>3, px = p&7;
            half8 a = *(const half8*)&H[((py+ky)*10 + (px+kx))*40 + qd*8];
#pragma unroll
            for (int nt = 0; nt < 2; ++nt)
                c2[nt][mt] = __builtin_amdgcn_mfma_f32_16x16x32_f16(a, wb[nt], c2[nt][mt], 0, 0, 0);
        }
    }
    // bias + gelu + mean-pool + fc
    float bias2[2] = { b2[r], b2[16+r] };
    float chs0 = 0.f, chs1 = 0.f;
#pragma unroll
    for (int mt = 0; mt < 4; ++mt)
#pragma unroll
      for (int j = 0; j < 4; ++j) {
        chs0 += geluf(c2[0][mt][j] + bias2[0]);
        chs1 += geluf(c2[1][mt][j] + bias2[1]);
      }
    chs0 += __shfl_xor(chs0, 16); chs0 += __shfl_xor(chs0, 32);
    chs1 += __shfl_xor(chs1, 16); chs1 += __shfl_xor(chs1, 32);
    float tot = (chs0 * fcw[r] + chs1 * fcw[16+r]) * (1.0f/64.0f);
    tot += __shfl_xor(tot, 1); tot += __shfl_xor(tot, 2);
    tot += __shfl_xor(tot, 4); tot += __shfl_xor(tot, 8);
    tot += fcb[0];
    if (lane == 0) {
        int t = img & 511, bk = img >> 9;
        int kk = bk % 12, bb = bk / 12;
        // faithful torch permutation: out[b, :, :].flat = scalars[b].T.flat
        outv[(bb*T_ + t)*12 + kk] = tot;
    }
}

extern "C" void kernel_launch(void* const* d_in, const int* in_sizes, int n_in,
                              void* d_out, int out_size, void* d_ws, size_t ws_size,
                              hipStream_t stream) {
    const float* mu   = (const float*)d_in[0];
    const float* sg0  = (const float*)d_in[1];
    const float* sgv  = (const float*)d_in[2];
    const float* amp  = (const float*)d_in[3];
    const float* shb  = (const float*)d_in[4];
    const float* shv  = (const float*)d_in[5];
    const float* p0   = (const float*)d_in[6];
    const float* pvel = (const float*)d_in[7];
    const float* taur = (const float*)d_in[8];
    const float* dar  = (const float*)d_in[9];
    const float* ra   = (const float*)d_in[10];
    const float* la   = (const float*)d_in[11];
    const float* ll   = (const float*)d_in[12];
    const float* chest= (const float*)d_in[13];
    const float* w1   = (const float*)d_in[14];
    const float* b1   = (const float*)d_in[15];
    const float* w2   = (const float*)d_in[16];
    const float* b2   = (const float*)d_in[17];
    const float* fcw  = (const float*)d_in[18];
    const float* fcb  = (const float*)d_in[19];

    char* ws = (char*)d_ws;
    _Float16*  W1p   = (_Float16*)ws;            // 2560 B
    _Float16*  W2p   = (_Float16*)(ws + 4096);   // 23040 B
    _Float16*  splat = (_Float16*)(ws + 32768);  // 6.29 MB

    splat_kernel<<<768, dim3(64,4), 0, stream>>>(mu, sg0, sgv, amp, shb, shv, p0, pvel,
                                                 taur, dar, ra, la, ll, chest, w1, w2,
                                                 splat, W1p, W2p);
    cnn_kernel<<<NIMG/4, 256, 0, stream>>>(splat, W1p, W2p, b1, b2, fcw, fcb, (float*)d_out);
}